// Round 17
// baseline (30.390 us; speedup 1.0000x reference)
//
#include <hip/hip_runtime.h>

// log sigma_{63,64} of exp(x) along classes: x (2048,10000) f32 -> out (2,2048) f32.
// Round 17: PERSISTENT 2-SAMPLE BLOCKS. Grid 1024 (4 blocks/CU, single
// generation, all resident). Block b handles samples b and b+1024:
// load(b) -> leaf(b) -> prefetch load(b+1024) -> tree(b) -> leaf -> tree.
// Sample-2 loads stream under sample-1 tree => no generation bubble.
// Leaf/tree bodies identical to round 16 (nt loads, verified absmax 0).

#define NS 2048
#define NC 10000
#define KSEL 64

typedef float f32x4 __attribute__((ext_vector_type(4)));

#define LOAD_PHASE(sidx)                                                                 \
  {                                                                                      \
    const f32x4* xv = (const f32x4*)(x + (size_t)(sidx) * NC);                           \
    _Pragma("unroll")                                                                    \
    for (int it = 0; it < 9; ++it) buf[it] = __builtin_nontemporal_load(&xv[t + it * 256]); \
    buf[9] = (f32x4){-1e30f, -1e30f, -1e30f, -1e30f};                                    \
    if (t < 196) buf[9] = __builtin_nontemporal_load(&xv[2304 + t]);                     \
  }

// Consume buf -> leaf poly, tau, RL1/RL2, store W2 row + red; then PREFETCH
// (next sample's loads) issues before the tree so they stream under it.
#define SAMPLE_PHASE(sidx, PREFETCH)                                                     \
  {                                                                                      \
    const int s = (sidx);                                                                \
    float c0 = 1.f, c1 = 0.f, c2 = 0.f, c3 = 0.f, c4 = 0.f, c5 = 0.f, c6 = 0.f;          \
    float sw = 0.f;                                                                      \
    _Pragma("unroll")                                                                    \
    for (int it = 0; it < 10; ++it) {                                                    \
      const f32x4 v = buf[it];                                                           \
      _Pragma("unroll")                                                                  \
      for (int q = 0; q < 4; ++q) {                                                      \
        const float xval = q == 0 ? v.x : q == 1 ? v.y : q == 2 ? v.z : v.w;             \
        const float w = __expf(xval);                                                    \
        sw += w;                                                                         \
        c6 = fmaf(w, c5, c6); c5 = fmaf(w, c4, c5); c4 = fmaf(w, c3, c4);                \
        c3 = fmaf(w, c2, c3); c2 = fmaf(w, c1, c2); c1 = fmaf(w, c0, c1);                \
      }                                                                                  \
    }                                                                                    \
    _Pragma("unroll")                                                                    \
    for (int m = 1; m < 64; m <<= 1) sw += __shfl_xor(sw, m);                            \
    if ((t & 63) == 0) red[wv] = sw;                                                     \
    __syncthreads();                                                                     \
    const float wsum = red[0] + red[1] + red[2] + red[3];                                \
    const float tau = __logf(wsum * ((float)(NC - KSEL) / ((float)KSEL * (float)NC)));   \
    {                                                                                    \
      const float f1 = __expf(-tau);                                                     \
      const float f2 = f1 * f1, f3 = f2 * f1, f4v = f2 * f2, f5 = f4v * f1, f6 = f4v * f2; \
      c1 *= f1; c2 *= f2; c3 *= f3; c4 *= f4v; c5 *= f5; c6 *= f6;                       \
    }                                                                                    \
    {                                                                                    \
      const float mx = fmaxf(fmaxf(fmaxf(c0, c1), fmaxf(c2, c3)), fmaxf(fmaxf(c4, c5), c6)); \
      const float invm = 1.f / mx;                                                       \
      c0 *= invm; c1 *= invm; c2 *= invm; c3 *= invm; c4 *= invm; c5 *= invm; c6 *= invm; \
      float Sr = __logf(mx);                                                             \
      _Pragma("unroll")                                                                  \
      for (int m = 1; m < 64; m <<= 1) Sr += __shfl_xor(Sr, m);                          \
      if ((t & 63) == 0) red[4 + wv] = Sr;                                               \
    }                                                                                    \
    const float q0 = __shfl_xor(c0, 1), q1 = __shfl_xor(c1, 1), q2 = __shfl_xor(c2, 1),  \
                q3 = __shfl_xor(c3, 1), q4 = __shfl_xor(c4, 1), q5 = __shfl_xor(c5, 1),  \
                q6 = __shfl_xor(c6, 1);                                                  \
    const float e0 = c0 * q0;                                                            \
    const float e1 = fmaf(c1, q0, c0 * q1);                                              \
    const float e2 = fmaf(c2, q0, fmaf(c1, q1, c0 * q2));                                \
    const float e3 = fmaf(c3, q0, fmaf(c2, q1, fmaf(c1, q2, c0 * q3)));                  \
    const float e4 = fmaf(c4, q0, fmaf(c3, q1, fmaf(c2, q2, fmaf(c1, q3, c0 * q4))));    \
    const float e5 = fmaf(c5, q0, fmaf(c4, q1, fmaf(c3, q2, fmaf(c2, q3, fmaf(c1, q4, c0 * q5))))); \
    const float e6 = fmaf(c6, q0, fmaf(c5, q1, fmaf(c4, q2, fmaf(c3, q3, fmaf(c2, q4, fmaf(c1, q5, c0 * q6)))))); \
    const float e7 = fmaf(c6, q1, fmaf(c5, q2, fmaf(c4, q3, fmaf(c3, q4, fmaf(c2, q5, c1 * q6))))); \
    const float f0 = __shfl_xor(e0, 2), f1 = __shfl_xor(e1, 2), f2 = __shfl_xor(e2, 2),  \
                f3 = __shfl_xor(e3, 2), f4 = __shfl_xor(e4, 2), f5 = __shfl_xor(e5, 2),  \
                f6 = __shfl_xor(e6, 2), f7 = __shfl_xor(e7, 2);                          \
    const float g0 = e0 * f0;                                                            \
    const float g1 = fmaf(e1, f0, e0 * f1);                                              \
    const float g2 = fmaf(e2, f0, fmaf(e1, f1, e0 * f2));                                \
    const float g3 = fmaf(e3, f0, fmaf(e2, f1, fmaf(e1, f2, e0 * f3)));                  \
    const float g4 = fmaf(e4, f0, fmaf(e3, f1, fmaf(e2, f2, fmaf(e1, f3, e0 * f4))));    \
    const float g5 = fmaf(e5, f0, fmaf(e4, f1, fmaf(e3, f2, fmaf(e2, f3, fmaf(e1, f4, e0 * f5))))); \
    const float g6 = fmaf(e6, f0, fmaf(e5, f1, fmaf(e4, f2, fmaf(e3, f3, fmaf(e2, f4, fmaf(e1, f5, e0 * f6)))))); \
    const float g7 = fmaf(e7, f0, fmaf(e6, f1, fmaf(e5, f2, fmaf(e4, f3, fmaf(e3, f4, fmaf(e2, f5, fmaf(e1, f6, e0 * f7))))))); \
    const float g8 = fmaf(e7, f1, fmaf(e6, f2, fmaf(e5, f3, fmaf(e4, f4, fmaf(e3, f5, fmaf(e2, f6, e1 * f7)))))); \
    const float g9 = fmaf(e7, f2, fmaf(e6, f3, fmaf(e5, f4, fmaf(e4, f5, fmaf(e3, f6, e2 * f7))))); \
    const float g10 = fmaf(e7, f3, fmaf(e6, f4, fmaf(e5, f5, fmaf(e4, f6, e3 * f7))));   \
    const float g11 = fmaf(e7, f4, fmaf(e6, f5, fmaf(e5, f6, e4 * f7)));                 \
    if ((t & 3) == 0) {                                                                  \
      float* row = W2 + (t >> 2) * 28;                                                   \
      *(float4*)(row)      = make_float4(0.f, 0.f, 0.f, 0.f);                            \
      *(float4*)(row + 4)  = make_float4(0.f, 0.f, 0.f, 0.f);                            \
      *(float4*)(row + 8)  = make_float4(0.f, 0.f, 0.f, g0);                             \
      *(float4*)(row + 12) = make_float4(g1, g2, g3, g4);                                \
      *(float4*)(row + 16) = make_float4(g5, g6, g7, g8);                                \
      *(float4*)(row + 20) = make_float4(g9, g10, g11, 0.f);                             \
      *(float4*)(row + 24) = make_float4(0.f, 0.f, 0.f, 0.f);                            \
    }                                                                                    \
    PREFETCH                                                                             \
    /* L3: 32 merges x 8 lanes; deg 11 -> keep 16 (reads own wave's W2) */               \
    {                                                                                    \
      const int m = t >> 3, r = t & 7;                                                   \
      const float* A = W2 + (2 * m) * 28;                                                \
      const float* B = W2 + (2 * m + 1) * 28;                                            \
      float o0 = 0.f, o1 = 0.f, o2 = 0.f;                                                \
      _Pragma("unroll")                                                                  \
      for (int i = 0; i <= 11; ++i) {                                                    \
        const float ai = A[11 + i];                                                      \
        o0 = fmaf(ai, B[11 + r - i], o0);                                                \
        o1 = fmaf(ai, B[19 + r - i], o1);                                                \
        o2 = fmaf(ai, B[27 - i], o2);                                                    \
      }                                                                                  \
      float mx = fmaxf(fmaxf(o0, o1), o2);                                               \
      mx = fmaxf(mx, __shfl_xor(mx, 1));                                                 \
      mx = fmaxf(mx, __shfl_xor(mx, 2));                                                 \
      mx = fmaxf(mx, __shfl_xor(mx, 4));                                                 \
      const float inv = 1.f / mx;                                                        \
      float* O = W3 + m * 37;                                                            \
      O[16 + r] = o0 * inv;                                                              \
      O[24 + r] = o1 * inv;                                                              \
      if (r == 0) { O[32] = o2 * inv; scLog[m] = __logf(mx); }                           \
      O[r] = 0.f; O[8 + r] = 0.f;                                                        \
      if (r < 4) O[33 + r] = 0.f;                                                        \
    }                                                                                    \
    /* L4: 16 merges x 16 lanes; deg 16 -> keep 20 */                                    \
    {                                                                                    \
      const int m = t >> 4, r = t & 15;                                                  \
      const float* A = W3 + (2 * m) * 37;                                                \
      const float* B = W3 + (2 * m + 1) * 37;                                            \
      float o0 = 0.f, o1 = 0.f;                                                          \
      _Pragma("unroll")                                                                  \
      for (int i = 0; i <= 16; ++i) {                                                    \
        const float ai = A[16 + i];                                                      \
        o0 = fmaf(ai, B[16 + r - i], o0);                                                \
        o1 = fmaf(ai, B[32 + r - i], o1);                                                \
      }                                                                                  \
      if (r >= 5) o1 = 0.f;                                                              \
      float mx = fmaxf(o0, o1);                                                          \
      mx = fmaxf(mx, __shfl_xor(mx, 1));                                                 \
      mx = fmaxf(mx, __shfl_xor(mx, 2));                                                 \
      mx = fmaxf(mx, __shfl_xor(mx, 4));                                                 \
      mx = fmaxf(mx, __shfl_xor(mx, 8));                                                 \
      const float inv = 1.f / mx;                                                        \
      float* O = W4 + m * 53;                                                            \
      O[20 + r] = o0 * inv;                                                              \
      if (r < 5) O[36 + r] = o1 * inv;                                                   \
      if (r == 0) scLog[32 + m] = __logf(mx);                                            \
      O[r] = 0.f;                                                                        \
      if (r < 4) O[16 + r] = 0.f;                                                        \
      if (r < 12) O[41 + r] = 0.f;                                                       \
    }                                                                                    \
    /* L5: 8 merges x 32 lanes; deg 20 -> keep 32 */                                     \
    {                                                                                    \
      const int m = t >> 5, p = t & 31;                                                  \
      const float* A = W4 + (2 * m) * 53;                                                \
      const float* B = W4 + (2 * m + 1) * 53;                                            \
      float o0 = 0.f, o1 = 0.f;                                                          \
      _Pragma("unroll")                                                                  \
      for (int i = 0; i <= 20; ++i) {                                                    \
        const float ai = A[20 + i];                                                      \
        o0 = fmaf(ai, B[20 + p - i], o0);                                                \
        o1 = fmaf(ai, B[52 - i], o1);                                                    \
      }                                                                                  \
      float mx = fmaxf(o0, o1);                                                          \
      mx = fmaxf(mx, __shfl_xor(mx, 1));                                                 \
      mx = fmaxf(mx, __shfl_xor(mx, 2));                                                 \
      mx = fmaxf(mx, __shfl_xor(mx, 4));                                                 \
      mx = fmaxf(mx, __shfl_xor(mx, 8));                                                 \
      mx = fmaxf(mx, __shfl_xor(mx, 16));                                                \
      const float inv = 1.f / mx;                                                        \
      float* O = W5 + m * 77;                                                            \
      O[32 + p] = o0 * inv;                                                              \
      if (p == 0) { O[64] = o1 * inv; scLog[48 + m] = __logf(mx); }                      \
      O[p] = 0.f;                                                                        \
      if (p < 12) O[65 + p] = 0.f;                                                       \
    }                                                                                    \
    /* L6: 4 merges x 64 lanes; deg 32 -> keep 44 */                                     \
    {                                                                                    \
      const int p = t & 63;                                                              \
      const float* A = W5 + (2 * wv) * 77;                                               \
      const float* B = W5 + (2 * wv + 1) * 77;                                           \
      float o0 = 0.f;                                                                    \
      _Pragma("unroll")                                                                  \
      for (int i = 0; i <= 32; ++i) {                                                    \
        const float ai = A[32 + i];                                                      \
        o0 = fmaf(ai, B[32 + p - i], o0);                                                \
      }                                                                                  \
      if (p >= 45) o0 = 0.f;                                                             \
      float mx = o0;                                                                     \
      _Pragma("unroll")                                                                  \
      for (int msk = 1; msk < 64; msk <<= 1) mx = fmaxf(mx, __shfl_xor(mx, msk));        \
      const float inv = 1.f / mx;                                                        \
      float* O = W6 + wv * 109;                                                          \
      if (p < 45) O[44 + p] = o0 * inv;                                                  \
      if (p == 0) scLog[56 + wv] = __logf(mx);                                           \
      if (p < 44) O[p] = 0.f;                                                            \
      if (p < 20) O[89 + p] = 0.f;                                                       \
    }                                                                                    \
    __syncthreads();                                                                     \
    /* L7: 2 merges, waves 0,1; deg 44 -> keep 64 */                                     \
    if (t < 128) {                                                                       \
      const int m = (t >> 6) & 1, p = t & 63;                                            \
      const float* A = W6 + (2 * m) * 109;                                               \
      const float* B = W6 + (2 * m + 1) * 109;                                           \
      float o0 = 0.f, o1 = 0.f;                                                          \
      _Pragma("unroll")                                                                  \
      for (int i = 0; i <= 44; ++i) {                                                    \
        const float ai = A[44 + i];                                                      \
        o0 = fmaf(ai, B[44 + p - i], o0);                                                \
        o1 = fmaf(ai, B[108 - i], o1);                                                   \
      }                                                                                  \
      float mx = fmaxf(o0, o1);                                                          \
      _Pragma("unroll")                                                                  \
      for (int msk = 1; msk < 64; msk <<= 1) mx = fmaxf(mx, __shfl_xor(mx, msk));        \
      const float inv = 1.f / mx;                                                        \
      float* O = W7 + m * 70;                                                            \
      O[p] = o0 * inv;                                                                   \
      if (p == 0) { O[64] = o1 * inv; scLog[60 + m] = __logf(mx); }                      \
    }                                                                                    \
    __syncthreads();                                                                     \
    /* L8: final degrees 63,64 + output */                                               \
    if (t < 64) {                                                                        \
      const float* A = W7;                                                               \
      const float* B = W7 + 70;                                                          \
      const float a = A[t];                                                              \
      float v63 = a * B[63 - t];                                                         \
      float v64 = a * B[64 - t];                                                         \
      float ee = (t < 62) ? scLog[t] : 0.f;                                              \
      _Pragma("unroll")                                                                  \
      for (int msk = 1; msk < 64; msk <<= 1) {                                           \
        v63 += __shfl_xor(v63, msk);                                                     \
        v64 += __shfl_xor(v64, msk);                                                     \
        ee  += __shfl_xor(ee, msk);                                                      \
      }                                                                                  \
      if (t == 0) {                                                                      \
        v64 = fmaf(A[64], B[0], v64);                                                    \
        const float Ssum = red[4] + red[5] + red[6] + red[7] + ee;                       \
        out[s]      = __logf(v63) + Ssum + 63.f * tau;                                   \
        out[NS + s] = __logf(v64) + Ssum + 64.f * tau;                                   \
      }                                                                                  \
    }                                                                                    \
  }

__global__ __launch_bounds__(256, 4)
void logesp_kernel(const float* __restrict__ x, float* __restrict__ out) {
  __shared__ float W2[64 * 28];
  __shared__ float W3[32 * 37];
  __shared__ float W4[16 * 53];
  __shared__ float W5[8 * 77];
  __shared__ float W6[4 * 109];
  __shared__ float W7[2 * 70];
  __shared__ float scLog[64];
  __shared__ float red[8];

  const int t  = threadIdx.x;
  const int wv = t >> 6;
  const int s0 = blockIdx.x;          // samples s0 and s0 + 1024
  const int s1 = blockIdx.x + (NS / 2);

  f32x4 buf[10];
  LOAD_PHASE(s0)
  SAMPLE_PHASE(s0, LOAD_PHASE(s1))    // prefetch s1 before s0's tree
  __syncthreads();                    // arena/scLog/red reuse boundary
  SAMPLE_PHASE(s1, )
}

extern "C" void kernel_launch(void* const* d_in, const int* in_sizes, int n_in,
                              void* d_out, int out_size, void* d_ws, size_t ws_size,
                              hipStream_t stream) {
  const float* x = (const float*)d_in[0];
  float* out = (float*)d_out;
  (void)in_sizes; (void)n_in; (void)d_ws; (void)ws_size; (void)out_size;
  logesp_kernel<<<NS / 2, 256, 0, stream>>>(x, out);
}

// Round 18
// 28.466 us; speedup vs baseline: 1.0676x; 1.0676x over previous
//
#include <hip/hip_runtime.h>

// log sigma_{63,64} of exp(x) along classes: x (2048,10000) f32 -> out (2,2048) f32.
// 256 threads/sample. Global exponential tilt tau; 256 register leaves (deg<=6),
// RL1/RL2 shuffle merges (deg 7, 11) -> L3..L7 static broadcast-convs in LDS
// (keep 16,20,32,44,64) -> L8 final degrees 63,64. Per-merge max-normalization,
// write-once scLog slots. 3 barriers (L3..L6 are wave-internal). nt input loads.
// Round 18 = exact revert to round 16 (best measured: 28.44 us, absmax 0).
// Round 17's persistent 2-sample prefetch regressed (30.4): holding 40 VGPRs of
// prefetch across the tree phase can't beat the ~2 us generation bubble.
// Status: ~90% of evidenced read roofline (80 MB / ~3.1 TB/s read-side ~= 25.4 us).

#define NS 2048
#define NC 10000
#define KSEL 64

typedef float f32x4 __attribute__((ext_vector_type(4)));

__global__ __launch_bounds__(256, 4)
void logesp_kernel(const float* __restrict__ x, float* __restrict__ out) {
  __shared__ float W2[64 * 28];   // leaf-quad polys: [11 z | c0..c11 | 5 z]
  __shared__ float W3[32 * 37];   // L3 out:          [16 z | c0..c16 | 4 z]
  __shared__ float W4[16 * 53];   // L4 out:          [20 z | c0..c20 | 12 z]
  __shared__ float W5[8 * 77];    // L5 out:          [32 z | c0..c32 | 12 z]
  __shared__ float W6[4 * 109];   // L6 out:          [44 z | c0..c44 | 20 z]
  __shared__ float W7[2 * 70];    // L7 out:          [c0..c64 | 5 pad]
  __shared__ float scLog[64];     // write-once: L3:0..31 L4:32..47 L5:48..55 L6:56..59 L7:60..61
  __shared__ float red[8];        // [0..3] per-wave sum(w); [4..7] per-wave sum(S)

  const int t  = threadIdx.x;
  const int wv = t >> 6;
  const int s  = blockIdx.x;

  // ---------- phase 1: leaf ESP deg<=6, all 10 loads batched up front (nt) ----------
  const f32x4* xv = (const f32x4*)(x + (size_t)s * NC);     // 2500 float4
  f32x4 buf[10];
#pragma unroll
  for (int it = 0; it < 9; ++it) buf[it] = __builtin_nontemporal_load(&xv[t + it * 256]);
  buf[9] = (f32x4){-1e30f, -1e30f, -1e30f, -1e30f};          // exp -> 0
  if (t < 196) buf[9] = __builtin_nontemporal_load(&xv[2304 + t]);   // 2304..2499

  float c0 = 1.f, c1 = 0.f, c2 = 0.f, c3 = 0.f, c4 = 0.f, c5 = 0.f, c6 = 0.f;
  float sw = 0.f;
#pragma unroll
  for (int it = 0; it < 10; ++it) {
    const f32x4 v = buf[it];
#pragma unroll
    for (int q = 0; q < 4; ++q) {
      const float xval = q == 0 ? v.x : q == 1 ? v.y : q == 2 ? v.z : v.w;
      const float w = __expf(xval);
      sw += w;
      c6 = fmaf(w, c5, c6);
      c5 = fmaf(w, c4, c5);
      c4 = fmaf(w, c3, c4);
      c3 = fmaf(w, c2, c3);
      c2 = fmaf(w, c1, c2);
      c1 = fmaf(w, c0, c1);   // c0 stays 1 (untilted leaf is f32-safe)
    }
  }

  // ---------- tilt tau = ln(wbar*(NC-K)/K) ----------
#pragma unroll
  for (int m = 1; m < 64; m <<= 1) sw += __shfl_xor(sw, m);
  if ((t & 63) == 0) red[wv] = sw;
  __syncthreads();                                   // barrier 1
  const float wsum = red[0] + red[1] + red[2] + red[3];
  const float tau = __logf(wsum * ((float)(NC - KSEL) / ((float)KSEL * (float)NC)));

  // tilt + leaf max-normalize (registers)
  {
    const float f1 = __expf(-tau);
    const float f2 = f1 * f1, f3 = f2 * f1, f4v = f2 * f2, f5 = f4v * f1, f6 = f4v * f2;
    c1 *= f1; c2 *= f2; c3 *= f3; c4 *= f4v; c5 *= f5; c6 *= f6;
  }
  {
    const float mx = fmaxf(fmaxf(fmaxf(c0, c1), fmaxf(c2, c3)), fmaxf(fmaxf(c4, c5), c6));
    const float invm = 1.f / mx;
    c0 *= invm; c1 *= invm; c2 *= invm; c3 *= invm; c4 *= invm; c5 *= invm; c6 *= invm;
    float Sr = __logf(mx);
#pragma unroll
    for (int m = 1; m < 64; m <<= 1) Sr += __shfl_xor(Sr, m);
    if ((t & 63) == 0) red[4 + wv] = Sr;             // read by L8 after barrier 2/3
  }

  // ---------- RL1: pair merge via shfl (deg 7) ----------
  const float q0 = __shfl_xor(c0, 1), q1 = __shfl_xor(c1, 1), q2 = __shfl_xor(c2, 1),
              q3 = __shfl_xor(c3, 1), q4 = __shfl_xor(c4, 1), q5 = __shfl_xor(c5, 1),
              q6 = __shfl_xor(c6, 1);
  const float e0 = c0 * q0;
  const float e1 = fmaf(c1, q0, c0 * q1);
  const float e2 = fmaf(c2, q0, fmaf(c1, q1, c0 * q2));
  const float e3 = fmaf(c3, q0, fmaf(c2, q1, fmaf(c1, q2, c0 * q3)));
  const float e4 = fmaf(c4, q0, fmaf(c3, q1, fmaf(c2, q2, fmaf(c1, q3, c0 * q4))));
  const float e5 = fmaf(c5, q0, fmaf(c4, q1, fmaf(c3, q2, fmaf(c2, q3, fmaf(c1, q4, c0 * q5)))));
  const float e6 = fmaf(c6, q0, fmaf(c5, q1, fmaf(c4, q2, fmaf(c3, q3, fmaf(c2, q4, fmaf(c1, q5, c0 * q6))))));
  const float e7 = fmaf(c6, q1, fmaf(c5, q2, fmaf(c4, q3, fmaf(c3, q4, fmaf(c2, q5, c1 * q6)))));

  // ---------- RL2: 4-leaf merge via shfl (deg 11) ----------
  const float f0 = __shfl_xor(e0, 2), f1 = __shfl_xor(e1, 2), f2 = __shfl_xor(e2, 2),
              f3 = __shfl_xor(e3, 2), f4 = __shfl_xor(e4, 2), f5 = __shfl_xor(e5, 2),
              f6 = __shfl_xor(e6, 2), f7 = __shfl_xor(e7, 2);
  const float g0 = e0 * f0;
  const float g1 = fmaf(e1, f0, e0 * f1);
  const float g2 = fmaf(e2, f0, fmaf(e1, f1, e0 * f2));
  const float g3 = fmaf(e3, f0, fmaf(e2, f1, fmaf(e1, f2, e0 * f3)));
  const float g4 = fmaf(e4, f0, fmaf(e3, f1, fmaf(e2, f2, fmaf(e1, f3, e0 * f4))));
  const float g5 = fmaf(e5, f0, fmaf(e4, f1, fmaf(e3, f2, fmaf(e2, f3, fmaf(e1, f4, e0 * f5)))));
  const float g6 = fmaf(e6, f0, fmaf(e5, f1, fmaf(e4, f2, fmaf(e3, f3, fmaf(e2, f4, fmaf(e1, f5, e0 * f6))))));
  const float g7 = fmaf(e7, f0, fmaf(e6, f1, fmaf(e5, f2, fmaf(e4, f3, fmaf(e3, f4, fmaf(e2, f5, fmaf(e1, f6, e0 * f7)))))));
  const float g8 = fmaf(e7, f1, fmaf(e6, f2, fmaf(e5, f3, fmaf(e4, f4, fmaf(e3, f5, fmaf(e2, f6, e1 * f7))))));
  const float g9 = fmaf(e7, f2, fmaf(e6, f3, fmaf(e5, f4, fmaf(e4, f5, fmaf(e3, f6, e2 * f7)))));
  const float g10 = fmaf(e7, f3, fmaf(e6, f4, fmaf(e5, f5, fmaf(e4, f6, e3 * f7))));
  const float g11 = fmaf(e7, f4, fmaf(e6, f5, fmaf(e5, f6, e4 * f7)));

  // store W2 row (quad q = t>>2): [11 z | g0..g11 | 5 z], 7 aligned float4
  if ((t & 3) == 0) {
    float* row = W2 + (t >> 2) * 28;
    *(float4*)(row)      = make_float4(0.f, 0.f, 0.f, 0.f);
    *(float4*)(row + 4)  = make_float4(0.f, 0.f, 0.f, 0.f);
    *(float4*)(row + 8)  = make_float4(0.f, 0.f, 0.f, g0);
    *(float4*)(row + 12) = make_float4(g1, g2, g3, g4);
    *(float4*)(row + 16) = make_float4(g5, g6, g7, g8);
    *(float4*)(row + 20) = make_float4(g9, g10, g11, 0.f);
    *(float4*)(row + 24) = make_float4(0.f, 0.f, 0.f, 0.f);
  }
  // L3 reads only rows written by its own wave -> no barrier (lgkmcnt ordering)

  // ---------- L3: 32 merges x 8 lanes; in deg 11 -> keep 16 ----------
  {
    const int m = t >> 3, r = t & 7;
    const float* A = W2 + (2 * m) * 28;
    const float* B = W2 + (2 * m + 1) * 28;
    float o0 = 0.f, o1 = 0.f, o2 = 0.f;            // degrees r, r+8, 16
#pragma unroll
    for (int i = 0; i <= 11; ++i) {
      const float ai = A[11 + i];
      o0 = fmaf(ai, B[11 + r - i], o0);            // idx 0..18
      o1 = fmaf(ai, B[19 + r - i], o1);            // idx 8..26
      o2 = fmaf(ai, B[27 - i], o2);                // idx 16..27 (same for all lanes)
    }
    float mx = fmaxf(fmaxf(o0, o1), o2);
    mx = fmaxf(mx, __shfl_xor(mx, 1));
    mx = fmaxf(mx, __shfl_xor(mx, 2));
    mx = fmaxf(mx, __shfl_xor(mx, 4));
    const float inv = 1.f / mx;
    float* O = W3 + m * 37;                         // [16 z | c0..c16 | 4 z]
    O[16 + r] = o0 * inv;
    O[24 + r] = o1 * inv;
    if (r == 0) { O[32] = o2 * inv; scLog[m] = __logf(mx); }
    O[r] = 0.f; O[8 + r] = 0.f;
    if (r < 4) O[33 + r] = 0.f;
  }

  // ---------- L4: 16 merges x 16 lanes; in deg 16 -> keep 20 ----------
  {
    const int m = t >> 4, r = t & 15;
    const float* A = W3 + (2 * m) * 37;
    const float* B = W3 + (2 * m + 1) * 37;
    float o0 = 0.f, o1 = 0.f;                       // degrees r, r+16 (r<5)
#pragma unroll
    for (int i = 0; i <= 16; ++i) {
      const float ai = A[16 + i];
      o0 = fmaf(ai, B[16 + r - i], o0);             // idx 0..31
      o1 = fmaf(ai, B[32 + r - i], o1);             // valid only r<5
    }
    if (r >= 5) o1 = 0.f;                           // discard garbage lanes
    float mx = fmaxf(o0, o1);
    mx = fmaxf(mx, __shfl_xor(mx, 1));
    mx = fmaxf(mx, __shfl_xor(mx, 2));
    mx = fmaxf(mx, __shfl_xor(mx, 4));
    mx = fmaxf(mx, __shfl_xor(mx, 8));
    const float inv = 1.f / mx;
    float* O = W4 + m * 53;                         // [20 z | c0..c20 | 12 z]
    O[20 + r] = o0 * inv;
    if (r < 5) O[36 + r] = o1 * inv;
    if (r == 0) scLog[32 + m] = __logf(mx);
    O[r] = 0.f;
    if (r < 4) O[16 + r] = 0.f;
    if (r < 12) O[41 + r] = 0.f;
  }

  // ---------- L5: 8 merges x 32 lanes; in deg 20 -> keep 32 ----------
  {
    const int m = t >> 5, p = t & 31;
    const float* A = W4 + (2 * m) * 53;
    const float* B = W4 + (2 * m + 1) * 53;
    float o0 = 0.f, o1 = 0.f;                       // degrees p, 32
#pragma unroll
    for (int i = 0; i <= 20; ++i) {
      const float ai = A[20 + i];
      o0 = fmaf(ai, B[20 + p - i], o0);             // idx 0..51
      o1 = fmaf(ai, B[52 - i], o1);                 // idx 31..52 (uniform)
    }
    float mx = fmaxf(o0, o1);
    mx = fmaxf(mx, __shfl_xor(mx, 1));
    mx = fmaxf(mx, __shfl_xor(mx, 2));
    mx = fmaxf(mx, __shfl_xor(mx, 4));
    mx = fmaxf(mx, __shfl_xor(mx, 8));
    mx = fmaxf(mx, __shfl_xor(mx, 16));
    const float inv = 1.f / mx;
    float* O = W5 + m * 77;                         // [32 z | c0..c32 | 12 z]
    O[32 + p] = o0 * inv;
    if (p == 0) { O[64] = o1 * inv; scLog[48 + m] = __logf(mx); }
    O[p] = 0.f;
    if (p < 12) O[65 + p] = 0.f;
  }

  // ---------- L6: 4 merges x 64 lanes; in deg 32 -> keep 44 ----------
  {
    const int p = t & 63;
    const float* A = W5 + (2 * wv) * 77;
    const float* B = W5 + (2 * wv + 1) * 77;
    float o0 = 0.f;                                 // degree p (<45)
#pragma unroll
    for (int i = 0; i <= 32; ++i) {
      const float ai = A[32 + i];
      o0 = fmaf(ai, B[32 + p - i], o0);             // idx 0..107 (masked below)
    }
    if (p >= 45) o0 = 0.f;
    float mx = o0;
#pragma unroll
    for (int msk = 1; msk < 64; msk <<= 1) mx = fmaxf(mx, __shfl_xor(mx, msk));
    const float inv = 1.f / mx;
    float* O = W6 + wv * 109;                       // [44 z | c0..c44 | 20 z]
    if (p < 45) O[44 + p] = o0 * inv;
    if (p == 0) scLog[56 + wv] = __logf(mx);
    if (p < 44) O[p] = 0.f;
    if (p < 20) O[89 + p] = 0.f;
  }
  __syncthreads();                                   // barrier 2 (cross-wave W6)

  // ---------- L7: 2 merges, waves 0,1; in deg 44 -> keep 64 ----------
  if (t < 128) {
    const int p = t & 63;
    const float* A = W6 + (2 * wv) * 109;
    const float* B = W6 + (2 * wv + 1) * 109;
    float o0 = 0.f, o1 = 0.f;                        // degrees p, 64
#pragma unroll
    for (int i = 0; i <= 44; ++i) {
      const float ai = A[44 + i];
      o0 = fmaf(ai, B[44 + p - i], o0);              // idx 0..107
      o1 = fmaf(ai, B[108 - i], o1);                 // idx 64..108 (uniform)
    }
    float mx = fmaxf(o0, o1);
#pragma unroll
    for (int msk = 1; msk < 64; msk <<= 1) mx = fmaxf(mx, __shfl_xor(mx, msk));
    const float inv = 1.f / mx;
    float* O = W7 + wv * 70;                         // [c0..c64 | pad]
    O[p] = o0 * inv;
    if (p == 0) { O[64] = o1 * inv; scLog[60 + wv] = __logf(mx); }
  }
  __syncthreads();                                   // barrier 3 (cross-wave W7)

  // ---------- L8: final degrees 63,64 + output ----------
  if (t < 64) {
    const float* A = W7;
    const float* B = W7 + 70;
    const float a = A[t];
    float v63 = a * B[63 - t];
    float v64 = a * B[64 - t];
    float ee = (t < 62) ? scLog[t] : 0.f;
#pragma unroll
    for (int msk = 1; msk < 64; msk <<= 1) {
      v63 += __shfl_xor(v63, msk);
      v64 += __shfl_xor(v64, msk);
      ee  += __shfl_xor(ee, msk);
    }
    if (t == 0) {
      v64 = fmaf(A[64], B[0], v64);
      const float Ssum = red[4] + red[5] + red[6] + red[7] + ee;
      out[s]      = __logf(v63) + Ssum + 63.f * tau;
      out[NS + s] = __logf(v64) + Ssum + 64.f * tau;
    }
  }
}

extern "C" void kernel_launch(void* const* d_in, const int* in_sizes, int n_in,
                              void* d_out, int out_size, void* d_ws, size_t ws_size,
                              hipStream_t stream) {
  const float* x = (const float*)d_in[0];
  float* out = (float*)d_out;
  (void)in_sizes; (void)n_in; (void)d_ws; (void)ws_size; (void)out_size;
  logesp_kernel<<<NS, 256, 0, stream>>>(x, out);
}